// Round 1
// baseline (2467.283 us; speedup 1.0000x reference)
//
#include <hip/hip_runtime.h>

typedef unsigned short u16;
typedef __bf16 bf16x8 __attribute__((ext_vector_type(8)));
typedef float f32x4 __attribute__((ext_vector_type(4)));

#define B_ 2
#define S_ 1024
#define H_ 4096
#define NH_ 32
#define HD_ 128
#define I_ 11008
#define M_ 2048          // B*S
#define NQKV 12288
#define NGU 22016

__device__ __forceinline__ u16 f2bf(float f) {
    union { float f; unsigned u; } v; v.f = f;
    unsigned r = v.u + 0x7fffu + ((v.u >> 16) & 1u);
    return (u16)(r >> 16);
}
__device__ __forceinline__ float bf2f(u16 h) {
    union { unsigned u; float f; } v; v.u = ((unsigned)h) << 16;
    return v.f;
}
__device__ __forceinline__ f32x4 zero4() { f32x4 z = {0.f, 0.f, 0.f, 0.f}; return z; }

// ---------------- transpose + fp32->bf16 convert: in[K][N] -> out[N][K] ----------------
__global__ void transpose_cvt(const float* __restrict__ in, u16* __restrict__ out, int K, int N) {
    __shared__ float tile[32][33];
    int n0 = blockIdx.x * 32, k0 = blockIdx.y * 32;
    int tx = threadIdx.x & 31, ty = threadIdx.x >> 5;   // 32 x 8
#pragma unroll
    for (int r = 0; r < 32; r += 8)
        tile[ty + r][tx] = in[(size_t)(k0 + ty + r) * N + n0 + tx];
    __syncthreads();
#pragma unroll
    for (int r = 0; r < 32; r += 8)
        out[(size_t)(n0 + ty + r) * K + k0 + tx] = f2bf(tile[tx][ty + r]);
}

// ---------------- rmsnorm: fp32 row -> bf16 row ----------------
__global__ void rmsnorm_k(const float* __restrict__ x, const float* __restrict__ w, u16* __restrict__ out) {
    int row = blockIdx.x;
    int tid = threadIdx.x;
    const float4* xr = (const float4*)(x + (size_t)row * H_);
    const float4* wr = (const float4*)w;
    float ss = 0.f;
#pragma unroll
    for (int i = tid; i < H_ / 4; i += 256) {
        float4 v = xr[i];
        ss += v.x * v.x + v.y * v.y + v.z * v.z + v.w * v.w;
    }
#pragma unroll
    for (int off = 32; off; off >>= 1) ss += __shfl_down(ss, off);
    __shared__ float wsum[4];
    if ((tid & 63) == 0) wsum[tid >> 6] = ss;
    __syncthreads();
    float tot = wsum[0] + wsum[1] + wsum[2] + wsum[3];
    float scale = rsqrtf(tot * (1.f / (float)H_) + 1e-6f);
    u16* orow = out + (size_t)row * H_;
    for (int i = tid; i < H_ / 4; i += 256) {
        float4 v = xr[i]; float4 wv = wr[i];
        union { u16 s[4]; uint2 v2; } pk;
        pk.s[0] = f2bf(v.x * scale * wv.x);
        pk.s[1] = f2bf(v.y * scale * wv.y);
        pk.s[2] = f2bf(v.z * scale * wv.z);
        pk.s[3] = f2bf(v.w * scale * wv.w);
        *(uint2*)(orow + i * 4) = pk.v2;
    }
}

// ---------------- GEMM: A[M][K] bf16 row-major, Bt[N][K] bf16 row-major ----------------
// 128x128 tile, BK=32, 4 waves each 64x64 (4x4 MFMA 16x16x32)
__global__ __launch_bounds__(256) void gemm128(
        const u16* __restrict__ A, const u16* __restrict__ Bt,
        float* __restrict__ outf, u16* __restrict__ outb,
        const float* __restrict__ bias, const float* __restrict__ res,
        int M, int N, int K) {
    __shared__ u16 As[128 * 40];
    __shared__ u16 Bs[128 * 40];
    int tid = threadIdx.x;
    int wave = tid >> 6, lane = tid & 63;
    int lm = lane & 15, quad = lane >> 4;
    int bm = blockIdx.y, bn = blockIdx.x;
    int wm = (wave >> 1) * 64, wn = (wave & 1) * 64;
    const u16* Ab = A + (size_t)bm * 128 * K;
    const u16* Bb = Bt + (size_t)bn * 128 * K;
    f32x4 acc[4][4];
#pragma unroll
    for (int i = 0; i < 4; ++i)
#pragma unroll
        for (int j = 0; j < 4; ++j) acc[i][j] = zero4();

    int r0 = tid >> 2;             // 0..63
    int c0 = (tid & 3) * 8;        // 0,8,16,24
    for (int k0 = 0; k0 < K; k0 += 32) {
        *(int4*)(As + r0 * 40 + c0)        = *(const int4*)(Ab + (size_t)r0 * K + k0 + c0);
        *(int4*)(As + (r0 + 64) * 40 + c0) = *(const int4*)(Ab + (size_t)(r0 + 64) * K + k0 + c0);
        *(int4*)(Bs + r0 * 40 + c0)        = *(const int4*)(Bb + (size_t)r0 * K + k0 + c0);
        *(int4*)(Bs + (r0 + 64) * 40 + c0) = *(const int4*)(Bb + (size_t)(r0 + 64) * K + k0 + c0);
        __syncthreads();
        bf16x8 af[4], bfr[4];
#pragma unroll
        for (int mi = 0; mi < 4; ++mi)
            af[mi] = *(const bf16x8*)(As + (wm + mi * 16 + lm) * 40 + quad * 8);
#pragma unroll
        for (int ni = 0; ni < 4; ++ni)
            bfr[ni] = *(const bf16x8*)(Bs + (wn + ni * 16 + lm) * 40 + quad * 8);
#pragma unroll
        for (int mi = 0; mi < 4; ++mi)
#pragma unroll
            for (int ni = 0; ni < 4; ++ni)
                acc[mi][ni] = __builtin_amdgcn_mfma_f32_16x16x32_bf16(af[mi], bfr[ni], acc[mi][ni], 0, 0, 0);
        __syncthreads();
    }
    // epilogue: C/D layout col=lane&15, row=quad*4+j
#pragma unroll
    for (int mi = 0; mi < 4; ++mi) {
#pragma unroll
        for (int ni = 0; ni < 4; ++ni) {
#pragma unroll
            for (int j = 0; j < 4; ++j) {
                int row = bm * 128 + wm + mi * 16 + quad * 4 + j;
                int col = bn * 128 + wn + ni * 16 + lm;
                float v = acc[mi][ni][j];
                if (bias) v += bias[col];
                if (res)  v += res[(size_t)row * N + col];
                if (outb) outb[(size_t)row * N + col] = f2bf(v);
                else      outf[(size_t)row * N + col] = v;
            }
        }
    }
}

// ---------------- RoPE on q and k: qkv[2048][12288] -> q_r,k_r [b][h][s][d] ----------------
__global__ void rope_k(const u16* __restrict__ qkv, const int* __restrict__ positions,
                       u16* __restrict__ q_r, u16* __restrict__ k_r) {
    int s = blockIdx.x & (S_ - 1);
    int b = blockIdx.x >> 10;
    float pos = (float)positions[s];
    const u16* row = qkv + (size_t)(b * S_ + s) * NQKV;
    int tid = threadIdx.x;
    for (int p = tid; p < NH_ * 64; p += 256) {
        int head = p >> 6, i = p & 63;
        float invf = expf(-(float)i * (9.210340371976184f / 64.f));   // 10000^(-i/64)
        float f = pos * invf;
        float sn, cs; sincosf(f, &sn, &cs);
        size_t obase = ((size_t)((b * NH_ + head) * S_ + s)) * HD_;
        float x1 = bf2f(row[head * HD_ + i]);
        float x2 = bf2f(row[head * HD_ + i + 64]);
        q_r[obase + i]      = f2bf(x1 * cs - x2 * sn);
        q_r[obase + i + 64] = f2bf(x2 * cs + x1 * sn);
        float y1 = bf2f(row[H_ + head * HD_ + i]);
        float y2 = bf2f(row[H_ + head * HD_ + i + 64]);
        k_r[obase + i]      = f2bf(y1 * cs - y2 * sn);
        k_r[obase + i + 64] = f2bf(y2 * cs + y1 * sn);
    }
}

// ---------------- V transpose: qkv v-part -> vT [b][h][d][s] ----------------
__global__ void vtrans_k(const u16* __restrict__ qkv, u16* __restrict__ vT) {
    int dt = blockIdx.x, st = blockIdx.y, bh = blockIdx.z;
    int b = bh >> 5, h = bh & 31;
    int tx = threadIdx.x & 31, ty = threadIdx.x >> 5;
    __shared__ u16 t[32][33];
#pragma unroll
    for (int r = 0; r < 32; r += 8) {
        int s = st * 32 + ty + r;
        t[ty + r][tx] = qkv[(size_t)(b * S_ + s) * NQKV + 2 * H_ + h * HD_ + dt * 32 + tx];
    }
    __syncthreads();
#pragma unroll
    for (int r = 0; r < 32; r += 8) {
        int d = dt * 32 + ty + r;
        vT[((size_t)bh * HD_ + d) * S_ + st * 32 + tx] = t[tx][ty + r];
    }
}

// ---------------- flash attention ----------------
// grid (qb=16, h=32, b=2); 256 threads; 64 q rows per block; K/V tiles of 64
__global__ __launch_bounds__(256) void attn_k(const u16* __restrict__ q_r, const u16* __restrict__ k_r,
                                              const u16* __restrict__ vT, u16* __restrict__ attn) {
    int qb = blockIdx.x, h = blockIdx.y, b = blockIdx.z;
    int tid = threadIdx.x, wave = tid >> 6, lane = tid & 63;
    int lm = lane & 15, quad = lane >> 4;
    __shared__ u16 Ks[64 * 136];
    __shared__ u16 Vts[128 * 72];
    __shared__ u16 Ps[4 * 16 * 72];
    size_t bh = (size_t)(b * NH_ + h);
    bf16x8 aq[4];
    {
        const u16* qptr = q_r + (bh * S_ + qb * 64 + wave * 16 + lm) * HD_;
#pragma unroll
        for (int c = 0; c < 4; ++c) aq[c] = *(const bf16x8*)(qptr + c * 32 + quad * 8);
    }
    f32x4 Ot[8];
#pragma unroll
    for (int t = 0; t < 8; ++t) Ot[t] = zero4();
    float m_i[4], l_i[4];
    int rq[4];
#pragma unroll
    for (int j = 0; j < 4; ++j) { m_i[j] = -1e30f; l_i[j] = 0.f; rq[j] = qb * 64 + wave * 16 + quad * 4 + j; }
    const float scale = 0.08838834764831845f;

    for (int kb = 0; kb <= qb; ++kb) {
        __syncthreads();
        const u16* kbase = k_r + (bh * S_ + kb * 64) * HD_;
        const u16* vbase = vT + bh * (HD_ * S_) + kb * 64;
#pragma unroll
        for (int it = 0; it < 4; ++it) {
            int lin = (it * 256 + tid) * 8;
            int r = lin >> 7, c = lin & 127;
            *(int4*)(Ks + r * 136 + c) = *(const int4*)(kbase + r * 128 + c);
            int d = lin >> 6, ss = lin & 63;
            *(int4*)(Vts + d * 72 + ss) = *(const int4*)(vbase + (size_t)d * S_ + ss);
        }
        __syncthreads();
        // S = Q K^T  (16 q rows x 64 keys per wave)
        f32x4 st[4];
#pragma unroll
        for (int nt = 0; nt < 4; ++nt) {
            st[nt] = zero4();
#pragma unroll
            for (int c = 0; c < 4; ++c) {
                bf16x8 bk = *(const bf16x8*)(Ks + (nt * 16 + lm) * 136 + c * 32 + quad * 8);
                st[nt] = __builtin_amdgcn_mfma_f32_16x16x32_bf16(aq[c], bk, st[nt], 0, 0, 0);
            }
        }
        float mloc[4] = {-1e30f, -1e30f, -1e30f, -1e30f};
#pragma unroll
        for (int nt = 0; nt < 4; ++nt) {
            int col = kb * 64 + nt * 16 + lm;
#pragma unroll
            for (int j = 0; j < 4; ++j) {
                float v = st[nt][j] * scale;
                if (col > rq[j]) v = -1e30f;
                st[nt][j] = v;
                mloc[j] = fmaxf(mloc[j], v);
            }
        }
#pragma unroll
        for (int j = 0; j < 4; ++j)
#pragma unroll
            for (int off = 1; off < 16; off <<= 1)
                mloc[j] = fmaxf(mloc[j], __shfl_xor(mloc[j], off));
        float alpha[4], lloc[4] = {0.f, 0.f, 0.f, 0.f};
#pragma unroll
        for (int j = 0; j < 4; ++j) {
            float mn = fmaxf(m_i[j], mloc[j]);
            alpha[j] = __expf(m_i[j] - mn);
            m_i[j] = mn;
        }
#pragma unroll
        for (int nt = 0; nt < 4; ++nt)
#pragma unroll
            for (int j = 0; j < 4; ++j) {
                float p = __expf(st[nt][j] - m_i[j]);
                st[nt][j] = p;
                lloc[j] += p;
            }
#pragma unroll
        for (int j = 0; j < 4; ++j) {
#pragma unroll
            for (int off = 1; off < 16; off <<= 1) lloc[j] += __shfl_xor(lloc[j], off);
            l_i[j] = l_i[j] * alpha[j] + lloc[j];
        }
#pragma unroll
        for (int t = 0; t < 8; ++t)
#pragma unroll
            for (int j = 0; j < 4; ++j) Ot[t][j] *= alpha[j];
        // P: C-layout -> LDS -> A-layout (per-wave buffer, padded stride 72)
        u16* pw = Ps + wave * 16 * 72;
#pragma unroll
        for (int nt = 0; nt < 4; ++nt)
#pragma unroll
            for (int j = 0; j < 4; ++j)
                pw[(quad * 4 + j) * 72 + nt * 16 + lm] = f2bf(st[nt][j]);
        bf16x8 ap0 = *(const bf16x8*)(pw + lm * 72 + quad * 8);
        bf16x8 ap1 = *(const bf16x8*)(pw + lm * 72 + 32 + quad * 8);
#pragma unroll
        for (int dt = 0; dt < 8; ++dt) {
            bf16x8 bv0 = *(const bf16x8*)(Vts + (dt * 16 + lm) * 72 + quad * 8);
            Ot[dt] = __builtin_amdgcn_mfma_f32_16x16x32_bf16(ap0, bv0, Ot[dt], 0, 0, 0);
            bf16x8 bv1 = *(const bf16x8*)(Vts + (dt * 16 + lm) * 72 + 32 + quad * 8);
            Ot[dt] = __builtin_amdgcn_mfma_f32_16x16x32_bf16(ap1, bv1, Ot[dt], 0, 0, 0);
        }
    }
#pragma unroll
    for (int j = 0; j < 4; ++j) l_i[j] = 1.f / l_i[j];
    u16* obase = attn + ((size_t)(b * S_)) * H_ + h * HD_;
#pragma unroll
    for (int dt = 0; dt < 8; ++dt)
#pragma unroll
        for (int j = 0; j < 4; ++j)
            obase[(size_t)rq[j] * H_ + dt * 16 + lm] = f2bf(Ot[dt][j] * l_i[j]);
}

// ---------------- SwiGLU: gu[2048][22016] -> hb[2048][11008] ----------------
__global__ void swiglu_k(const u16* __restrict__ gu, u16* __restrict__ hb) {
    int idx = blockIdx.x * 256 + threadIdx.x;       // 2048*11008/8 threads
    int r = idx / (I_ / 8);
    int c = (idx % (I_ / 8)) * 8;
    const u16* grow = gu + (size_t)r * NGU;
    int4 gv = *(const int4*)(grow + c);
    int4 uv = *(const int4*)(grow + I_ + c);
    const u16* gs = (const u16*)&gv;
    const u16* us = (const u16*)&uv;
    union { u16 o[8]; int4 v; } pk;
#pragma unroll
    for (int j = 0; j < 8; ++j) {
        float g = bf2f(gs[j]);
        float u = bf2f(us[j]);
        float sg = g / (1.f + __expf(-g));
        pk.o[j] = f2bf(sg * u);
    }
    *(int4*)(hb + (size_t)r * I_ + c) = pk.v;
}

// ---------------- launch ----------------
extern "C" void kernel_launch(void* const* d_in, const int* in_sizes, int n_in,
                              void* d_out, int out_size, void* d_ws, size_t ws_size,
                              hipStream_t stream) {
    (void)in_sizes; (void)n_in; (void)out_size; (void)ws_size;
    const int*   positions = (const int*)d_in[0];
    const float* hidden    = (const float*)d_in[1];
    const float* ln1       = (const float*)d_in[2];
    const float* ln2       = (const float*)d_in[3];
    const float* w_qkv     = (const float*)d_in[4];
    const float* b_qkv     = (const float*)d_in[5];
    const float* w_o       = (const float*)d_in[6];
    const float* w_gu      = (const float*)d_in[7];
    const float* w_down    = (const float*)d_in[8];
    float* out = (float*)d_out;
    char* ws = (char*)d_ws;

    // workspace layout (bytes); buffers overlapped by liveness
    const size_t off_wqkvT = 0;                           // [12288][4096] bf16
    const size_t off_woT   = 100663296;                   // [4096][4096]  bf16
    const size_t off_wguT  = 134217728;                   // [22016][4096] bf16
    const size_t off_wdT   = 314572800;                   // [4096][11008] bf16
    const size_t off_xb    = 404750336;                   // [2048][4096]  bf16 (later aliased by gu)
    const size_t off_qkv   = 421527552;                   // [2048][12288] bf16
    const size_t off_q     = 471859200;                   // [b][h][s][d]  bf16
    const size_t off_k     = 488636416;                   // [b][h][s][d]  bf16
    const size_t off_x2    = 505413632;                   // [2048][4096]  fp32
    const size_t off_vT    = 538968064;                   // [b][h][d][s]  bf16 (later aliased by hb)
    const size_t off_attn  = 555745280;                   // [2048][4096]  bf16
    const size_t off_xb2   = 572522496;                   // [2048][4096]  bf16
    const size_t off_gu    = off_xb;                      // [2048][22016] bf16 (xb/qkv/q/k dead)
    const size_t off_hb    = off_vT;                      // [2048][11008] bf16 (vT/attn/xb2 dead)

    u16*   wqkvT = (u16*)(ws + off_wqkvT);
    u16*   woT   = (u16*)(ws + off_woT);
    u16*   wguT  = (u16*)(ws + off_wguT);
    u16*   wdT   = (u16*)(ws + off_wdT);
    u16*   xb    = (u16*)(ws + off_xb);
    u16*   qkvb  = (u16*)(ws + off_qkv);
    u16*   q_r   = (u16*)(ws + off_q);
    u16*   k_r   = (u16*)(ws + off_k);
    float* x2    = (float*)(ws + off_x2);
    u16*   vT    = (u16*)(ws + off_vT);
    u16*   attnb = (u16*)(ws + off_attn);
    u16*   xb2   = (u16*)(ws + off_xb2);
    u16*   gu    = (u16*)(ws + off_gu);
    u16*   hb    = (u16*)(ws + off_hb);

    // 1. weight convert+transpose
    transpose_cvt<<<dim3(NQKV / 32, H_ / 32), 256, 0, stream>>>(w_qkv, wqkvT, H_, NQKV);
    transpose_cvt<<<dim3(H_ / 32, H_ / 32), 256, 0, stream>>>(w_o, woT, H_, H_);
    transpose_cvt<<<dim3(NGU / 32, H_ / 32), 256, 0, stream>>>(w_gu, wguT, H_, NGU);
    transpose_cvt<<<dim3(H_ / 32, I_ / 32), 256, 0, stream>>>(w_down, wdT, I_, H_);
    // 2. rmsnorm 1
    rmsnorm_k<<<M_, 256, 0, stream>>>(hidden, ln1, xb);
    // 3. qkv gemm (+bias, bf16 out)
    gemm128<<<dim3(NQKV / 128, M_ / 128), 256, 0, stream>>>(xb, wqkvT, nullptr, qkvb, b_qkv, nullptr, M_, NQKV, H_);
    // 4. rope q,k ; 5. v transpose
    rope_k<<<M_, 256, 0, stream>>>(qkvb, positions, q_r, k_r);
    vtrans_k<<<dim3(HD_ / 32, S_ / 32, B_ * NH_), 256, 0, stream>>>(qkvb, vT);
    // 6. attention
    attn_k<<<dim3(S_ / 64, NH_, B_), 256, 0, stream>>>(q_r, k_r, vT, attnb);
    // 7. o proj + residual -> x2 (fp32)
    gemm128<<<dim3(H_ / 128, M_ / 128), 256, 0, stream>>>(attnb, woT, x2, nullptr, nullptr, hidden, M_, H_, H_);
    // 8. rmsnorm 2
    rmsnorm_k<<<M_, 256, 0, stream>>>(x2, ln2, xb2);
    // 9. gate_up gemm (bf16 out)
    gemm128<<<dim3(NGU / 128, M_ / 128), 256, 0, stream>>>(xb2, wguT, nullptr, gu, nullptr, nullptr, M_, NGU, H_);
    // 10. swiglu
    swiglu_k<<<(M_ * I_ / 8) / 256, 256, 0, stream>>>(gu, hb);
    // 11. down gemm + residual -> out (fp32)
    gemm128<<<dim3(H_ / 128, M_ / 128), 256, 0, stream>>>(hb, wdT, out, nullptr, nullptr, x2, M_, H_, I_);
}